// Round 14
// baseline (1557.921 us; speedup 1.0000x reference)
//
#include <hip/hip_runtime.h>

// Problem constants (match reference setup_inputs)
constexpr int NV = 100000;   // vertices
constexpr int NE = 1600000;  // directed edges
constexpr int NB = 64;       // graphs
constexpr int HD = 128;      // hidden
constexpr int DM = 256;      // out dim
#define EPSLN 1e-5f

// CSR bucketing (fixed-capacity bucket regions)
constexpr int DPB   = 256;                      // dsts per bucket
constexpr int NBUCK = (NV + DPB - 1) / DPB;     // 391
constexpr int BCAP  = 8192;                     // per-bucket capacity (mean 4092, >>6 sigma)
constexpr int BSH   = 13;                       // log2(BCAP)
constexpr int EPB2  = 2048;                     // edges per block (scatter part of k_init)
constexpr int NEB2  = (NE + EPB2 - 1) / EPB2;   // 782
constexpr int H1B   = 1024;                     // h1 blocks
constexpr int WTB   = 128;                      // wt-transpose blocks
constexpr int BDB   = (NV + 255) / 256;         // batch-boundary blocks (391)

typedef short bf16x8 __attribute__((ext_vector_type(8)));
typedef float f32x4 __attribute__((ext_vector_type(4)));

__device__ inline unsigned short f2b(float f) {
    union { float f; unsigned u; } x; x.f = f;
    unsigned r = x.u + 0x7FFF + ((x.u >> 16) & 1);
    return (unsigned short)(r >> 16);
}
__device__ inline float b2f(unsigned short h) {
    union { unsigned u; float f; } x; x.u = (unsigned)h << 16;
    return x.f;
}

// ---------- fused init: scatter | layer-1 H | W transpose | batch boundaries ----------
__global__ __launch_bounds__(256) void k_init(const float* __restrict__ verts,
                                              const float* __restrict__ Win,
                                              const float* __restrict__ bin,
                                              const float* __restrict__ W1,
                                              const float* __restrict__ W2,
                                              const float* __restrict__ W3,
                                              const int* __restrict__ ei,
                                              const int* __restrict__ batch,
                                              int* __restrict__ bcursor,
                                              int* __restrict__ ebuf,
                                              unsigned short* __restrict__ Hb,
                                              unsigned short* __restrict__ Wt,
                                              int* __restrict__ gstart,
                                              int* __restrict__ gend) {
    int t = threadIdx.x;
    int bid = blockIdx.x;
    if (bid < NEB2) {
        // ---- scatter edges into fixed-capacity bucket regions ----
        __shared__ int h[NBUCK];
        __shared__ int lbase[NBUCK];
        for (int i = t; i < NBUCK; i += 256) h[i] = 0;
        __syncthreads();
        int base = bid * EPB2;
        int s[8], d[8], rk[8];
        #pragma unroll
        for (int j = 0; j < 8; ++j) {
            int idx = base + j * 256 + t;
            if (idx < NE) {
                s[j] = ei[idx];
                d[j] = ei[NE + idx];
                rk[j] = atomicAdd(&h[d[j] >> 8], 1);
            } else d[j] = -1;
        }
        __syncthreads();
        for (int i = t; i < NBUCK; i += 256) {
            int c = h[i];
            if (c) lbase[i] = atomicAdd(&bcursor[i], c);
        }
        __syncthreads();
        #pragma unroll
        for (int j = 0; j < 8; ++j)
            if (d[j] >= 0) {
                int b = d[j] >> 8;
                ebuf[(b << BSH) + lbase[b] + rk[j]] = (s[j] << 8) | (d[j] & 255);
            }
        return;
    }
    if (bid < NEB2 + H1B) {
        // ---- layer-1 H from vertices; folds Wc = Win@W1, bc = bin@W1 ----
        __shared__ float Wc[3 * HD];
        __shared__ float bc[HD];
        if (t < HD) {
            float w0 = 0.f, w1 = 0.f, w2 = 0.f, bv = 0.f;
            for (int k = 0; k < HD; ++k) {
                float w = W1[k * HD + t];
                w0 = fmaf(Win[k], w, w0);
                w1 = fmaf(Win[128 + k], w, w1);
                w2 = fmaf(Win[256 + k], w, w2);
                bv = fmaf(bin[k], w, bv);
            }
            Wc[t] = w0; Wc[128 + t] = w1; Wc[256 + t] = w2; bc[t] = bv;
        }
        __syncthreads();
        for (int idx = (bid - NEB2) * 256 + t; idx < NV * HD; idx += H1B * 256) {
            int v = idx >> 7, c = idx & 127;
            float a = verts[v * 3 + 0], b = verts[v * 3 + 1], d = verts[v * 3 + 2];
            Hb[idx] = f2b(bc[c] + a * Wc[c] + b * Wc[128 + c] + d * Wc[256 + c]);
        }
        return;
    }
    if (bid < NEB2 + H1B + WTB) {
        // ---- W2,W3 [k][n] f32 -> Wt [l][n][k] bf16 ----
        int idx = (bid - NEB2 - H1B) * 256 + t;   // 0..32767
        if (idx < 2 * HD * HD) {
            int l = idx >> 14, r = idx & 16383;
            const float* W = (l == 0) ? W2 : W3;
            int n = r >> 7, k = r & 127;
            Wt[(l << 14) + n * HD + k] = f2b(W[k * HD + n]);
        }
        return;
    }
    // ---- batch boundary detection (plain stores; batch is sorted) ----
    int i = (bid - NEB2 - H1B - WTB) * 256 + t;
    if (i < NV) {
        int b = batch[i];
        if (i == 0 || batch[i - 1] != b) gstart[b] = i;
        int bn = (i + 1 < NV) ? batch[i + 1] : -1;
        if (bn != b) gend[b] = i + 1;
    }
}

// ---------- per-bucket CSR: LDS-staged edges, hist -> scan -> fill ----------
__global__ __launch_bounds__(256) void k_bcsr(const int* __restrict__ ebuf,
                                              const int* __restrict__ bcursor,
                                              int* __restrict__ degi,
                                              float* __restrict__ dinv,
                                              int* __restrict__ rowstart,
                                              int* __restrict__ csr) {
    __shared__ int els[BCAP];
    __shared__ int h[DPB];
    __shared__ int sdata[DPB];
    int b = blockIdx.x, t = threadIdx.x, d0 = b * DPB;
    h[t] = 0;
    __syncthreads();
    int e0 = b << BSH;
    int n = bcursor[b];
    for (int i = t; i < n; i += 256) {
        int p = ebuf[e0 + i];
        if (i < BCAP) els[i] = p;
        atomicAdd(&h[p & 255], 1);
    }
    __syncthreads();
    int a = h[t];
    sdata[t] = a;
    __syncthreads();
    for (int off = 1; off < 256; off <<= 1) {
        int v = sdata[t];
        int add = (t >= off) ? sdata[t - off] : 0;
        __syncthreads();
        sdata[t] = v + add;
        __syncthreads();
    }
    int excl = (t == 0) ? 0 : sdata[t - 1];
    int v0 = d0 + t;
    if (v0 < NV) {
        rowstart[v0] = e0 + excl;
        degi[v0] = a;
        dinv[v0] = rsqrtf((float)a + 1.0f);
    }
    h[t] = e0 + excl;
    __syncthreads();
    for (int i = t; i < n; i += 256) {
        int p = (i < BCAP) ? els[i] : ebuf[e0 + i];
        int slot = atomicAdd(&h[p & 255], 1);
        csr[slot] = p >> 8;
    }
}

// ---------- H = X @ W via MFMA; Wt staged in padded LDS; coalesced epilogue ----------
__global__ __launch_bounds__(256) void k_gemm_mfma(const unsigned short* __restrict__ Xb,
                                                   const unsigned short* __restrict__ Wt,
                                                   unsigned short* __restrict__ Hb) {
    __shared__ __align__(16) unsigned short Ws[128 * 132];   // padded rows: bank-spread
    __shared__ __align__(16) unsigned short hs[4][16][136];  // per-wave repack buffer
    int t = threadIdx.x;
    {   // stage Wt -> LDS
        int row = t >> 1;
        int half = (t & 1) << 6;
        const unsigned short* src = Wt + row * HD + half;
        unsigned short* dst = &Ws[row * 132 + half];
        #pragma unroll
        for (int i = 0; i < 8; ++i)
            *(bf16x8*)(dst + i * 8) = *(const bf16x8*)(src + i * 8);
    }
    int wave = t >> 6;
    int lane = t & 63;
    int r = lane & 15;
    int g = lane >> 4;                     // 0..3
    int row0 = blockIdx.x * 64 + wave * 16;
    int arow = row0 + r;
    bool valid = arow < NV;

    bf16x8 afrag[4];
    const unsigned short* xp = Xb + (size_t)arow * HD + g * 8;
    #pragma unroll
    for (int ks = 0; ks < 4; ++ks) {
        if (valid) afrag[ks] = *(const bf16x8*)(xp + ks * 32);
        else       afrag[ks] = bf16x8{0, 0, 0, 0, 0, 0, 0, 0};
    }
    __syncthreads();

    #pragma unroll
    for (int nt = 0; nt < 8; ++nt) {
        f32x4 acc = {0.f, 0.f, 0.f, 0.f};
        #pragma unroll
        for (int ks = 0; ks < 4; ++ks) {
            bf16x8 bfrag = *(const bf16x8*)&Ws[(nt * 16 + r) * 132 + g * 8 + ks * 32];
            acc = __builtin_amdgcn_mfma_f32_16x16x32_bf16(afrag[ks], bfrag, acc, 0, 0, 0);
        }
        #pragma unroll
        for (int j = 0; j < 4; ++j)
            hs[wave][g * 4 + j][nt * 16 + r] = f2b(acc[j]);
    }
    int row = lane >> 2;
    int grow = row0 + row;
    #pragma unroll
    for (int k = 0; k < 4; ++k) {
        int c = (lane & 3) + k * 4;      // chunk 0..15 (8 shorts each)
        bf16x8 val = *(const bf16x8*)&hs[wave][row][c * 8];
        if (grow < NV)
            *(bf16x8*)(Hb + (size_t)grow * HD + c * 8) = val;
    }
}

// ---------- aggregate: one wave per dst, quarter-waves; POOL=1 fuses mean-pool ----------
template <int POOL>
__global__ __launch_bounds__(256) void k_agg(const unsigned short* __restrict__ H,
                                             const float* __restrict__ dinv,
                                             const int* __restrict__ rowstart,
                                             const int* __restrict__ degi,
                                             const int* __restrict__ csr_src,
                                             const float* __restrict__ bias,
                                             unsigned short* __restrict__ Xo,
                                             const int* __restrict__ batch,
                                             float* __restrict__ poolr) {
    int gtid = blockIdx.x * 256 + threadIdx.x;
    int v = gtid >> 6;
    if (v >= NV) return;
    int lane = threadIdx.x & 63;
    int q = lane >> 4;        // quarter 0..3: edges q, q+4, ...
    int l4 = lane & 15;       // col group: cols l4*8 .. l4*8+7
    float di = dinv[v];
    int rs = rowstart[v], len = degi[v];
    float a[8];
    if (q == 0) {
        float sc = di * di;
        bf16x8 hv = *(const bf16x8*)(H + (size_t)v * HD + l4 * 8);
        #pragma unroll
        for (int jj = 0; jj < 8; ++jj) a[jj] = b2f((unsigned short)hv[jj]) * sc;
    } else {
        #pragma unroll
        for (int jj = 0; jj < 8; ++jj) a[jj] = 0.f;
    }
    int cnt = (len - q + 3) >> 2;   // edges this quarter handles
    int idx = rs + q;
    int j = 0;
    for (; j + 1 < cnt; j += 2) {
        int s0 = csr_src[idx], s1 = csr_src[idx + 4];
        idx += 8;
        float w0 = dinv[s0] * di, w1 = dinv[s1] * di;
        bf16x8 h0 = *(const bf16x8*)(H + (size_t)s0 * HD + l4 * 8);
        bf16x8 h1 = *(const bf16x8*)(H + (size_t)s1 * HD + l4 * 8);
        #pragma unroll
        for (int jj = 0; jj < 8; ++jj) {
            a[jj] = fmaf(b2f((unsigned short)h0[jj]), w0, a[jj]);
            a[jj] = fmaf(b2f((unsigned short)h1[jj]), w1, a[jj]);
        }
    }
    if (j < cnt) {
        int s0 = csr_src[idx];
        float w0 = dinv[s0] * di;
        bf16x8 h0 = *(const bf16x8*)(H + (size_t)s0 * HD + l4 * 8);
        #pragma unroll
        for (int jj = 0; jj < 8; ++jj)
            a[jj] = fmaf(b2f((unsigned short)h0[jj]), w0, a[jj]);
    }
    // reduce across quarters (lanes l4, l4+16, l4+32, l4+48)
    #pragma unroll
    for (int jj = 0; jj < 8; ++jj) {
        a[jj] += __shfl_xor(a[jj], 16);
        a[jj] += __shfl_xor(a[jj], 32);
    }
    if (q == 0) {
        if (POOL) {
            int gb = batch[v];
            float* pr = poolr + ((size_t)(blockIdx.x & 7) * NB + gb) * HD + l4 * 8;
            #pragma unroll
            for (int jj = 0; jj < 8; ++jj)
                atomicAdd(&pr[jj], fmaxf(a[jj] + bias[l4 * 8 + jj], 0.f));
        } else {
            bf16x8 ov;
            #pragma unroll
            for (int jj = 0; jj < 8; ++jj)
                ov[jj] = (short)f2b(fmaxf(a[jj] + bias[l4 * 8 + jj], 0.f));
            *(bf16x8*)(Xo + (size_t)v * HD + l4 * 8) = ov;
        }
    }
}

// ---------- final: sum pool replicas, mean, linear, layernorm; one block/graph ----------
__global__ __launch_bounds__(256) void k_out(const float* __restrict__ poolr,
                                             const int* __restrict__ gstart,
                                             const int* __restrict__ gend,
                                             const float* __restrict__ Wout,
                                             const float* __restrict__ bout,
                                             const float* __restrict__ gamma,
                                             const float* __restrict__ beta,
                                             float* __restrict__ out) {
    __shared__ float ps[HD];
    __shared__ float red[DM];
    int g = blockIdx.x, t = threadIdx.x;
    if (t < HD) {
        float s = 0.f;
        #pragma unroll
        for (int r = 0; r < 8; ++r)
            s += poolr[((size_t)r * NB + g) * HD + t];
        float cn = fmaxf((float)(gend[g] - gstart[g]), 1.0f);
        ps[t] = s / cn;
    }
    __syncthreads();
    float acc = bout[t];
    #pragma unroll 8
    for (int k = 0; k < HD; ++k) acc = fmaf(ps[k], Wout[k * DM + t], acc);
    red[t] = acc; __syncthreads();
    for (int s2 = 128; s2 > 0; s2 >>= 1) {
        if (t < s2) red[t] += red[t + s2];
        __syncthreads();
    }
    float mu = red[0] * (1.0f / DM);
    __syncthreads();
    float d = acc - mu;
    red[t] = d * d; __syncthreads();
    for (int s2 = 128; s2 > 0; s2 >>= 1) {
        if (t < s2) red[t] += red[t + s2];
        __syncthreads();
    }
    float var = red[0] * (1.0f / DM);
    out[g * DM + t] = d * rsqrtf(var + EPSLN) * gamma[t] + beta[t];
}

extern "C" void kernel_launch(void* const* d_in, const int* in_sizes, int n_in,
                              void* d_out, int out_size, void* d_ws, size_t ws_size,
                              hipStream_t stream) {
    const float* verts = (const float*)d_in[0];
    const int*   ei    = (const int*)d_in[1];
    const int*   batch = (const int*)d_in[2];
    const float* Win   = (const float*)d_in[3];
    const float* bin   = (const float*)d_in[4];
    const float* W1    = (const float*)d_in[5];
    const float* b1    = (const float*)d_in[6];
    const float* W2    = (const float*)d_in[7];
    const float* b2    = (const float*)d_in[8];
    const float* W3    = (const float*)d_in[9];
    const float* b3    = (const float*)d_in[10];
    const float* Wout  = (const float*)d_in[11];
    const float* bout  = (const float*)d_in[12];
    const float* gamma = (const float*)d_in[13];
    const float* beta  = (const float*)d_in[14];
    float* out = (float*)d_out;

    char* wp = (char*)d_ws;
    auto alloc = [&](size_t bytes) -> char* {
        char* p = wp;
        wp += (bytes + 255) & ~(size_t)255;
        return p;
    };
    unsigned short* bufA = (unsigned short*)alloc((size_t)NV * HD * 2);
    unsigned short* bufB = (unsigned short*)alloc((size_t)NV * HD * 2);
    unsigned short* Wt   = (unsigned short*)alloc((size_t)2 * HD * HD * 2);
    int*   degi     = (int*)alloc((size_t)NV * 4);
    float* dinv     = (float*)alloc((size_t)NV * 4);
    int*   rowstart = (int*)alloc((size_t)NV * 4);
    int*   csr      = (int*)alloc((size_t)NBUCK * BCAP * 4);
    int*   ebuf     = (int*)alloc((size_t)NBUCK * BCAP * 4);
    // contiguous zero region: bcursor | poolr (8 replicas) | gstart | gend
    size_t zb_cursor = ((size_t)NBUCK * 4 + 255) & ~(size_t)255;
    size_t zb_poolr  = (size_t)8 * NB * HD * 4;
    size_t zb_tot    = zb_cursor + zb_poolr + 1024;
    char*  zblock   = alloc(zb_tot);
    int*   bcursor  = (int*)zblock;
    float* poolr    = (float*)(zblock + zb_cursor);
    int*   gstart   = (int*)(zblock + zb_cursor + zb_poolr);
    int*   gend     = (int*)(zblock + zb_cursor + zb_poolr + 512);

    hipMemsetAsync(zblock, 0, zb_tot, stream);

    // fused init: edge scatter + layer-1 H + W transpose + batch boundaries
    k_init<<<NEB2 + H1B + WTB + BDB, 256, 0, stream>>>(verts, Win, bin, W1, W2, W3,
                                                       ei, batch, bcursor, ebuf,
                                                       bufA, Wt, gstart, gend);
    // per-bucket CSR build (LDS-staged)
    k_bcsr<<<NBUCK, 256, 0, stream>>>(ebuf, bcursor, degi, dinv, rowstart, csr);

    int aggrid = (int)(((size_t)NV * 64 + 255) / 256);
    // layer 1
    k_agg<0><<<aggrid, 256, 0, stream>>>(bufA, dinv, rowstart, degi, csr, b1, bufB, batch, poolr);
    k_gemm_mfma<<<(NV + 63) / 64, 256, 0, stream>>>(bufB, Wt, bufA);
    // layer 2
    k_agg<0><<<aggrid, 256, 0, stream>>>(bufA, dinv, rowstart, degi, csr, b2, bufB, batch, poolr);
    k_gemm_mfma<<<(NV + 63) / 64, 256, 0, stream>>>(bufB, Wt + (size_t)HD * HD, bufA);
    // layer 3 (+ fused mean-pool accumulation, f32)
    k_agg<1><<<aggrid, 256, 0, stream>>>(bufA, dinv, rowstart, degi, csr, b3, bufB, batch, poolr);

    k_out<<<NB, 256, 0, stream>>>(poolr, gstart, gend, Wout, bout, gamma, beta, out);
}

// Round 15
// 340.333 us; speedup vs baseline: 4.5776x; 4.5776x over previous
//
#include <hip/hip_runtime.h>

// Problem constants (match reference setup_inputs)
constexpr int NV = 100000;   // vertices
constexpr int NE = 1600000;  // directed edges
constexpr int NB = 64;       // graphs
constexpr int HD = 128;      // hidden
constexpr int DM = 256;      // out dim
#define EPSLN 1e-5f

// CSR bucketing (fixed-capacity bucket regions)
constexpr int DPB   = 256;                      // dsts per bucket
constexpr int NBUCK = (NV + DPB - 1) / DPB;     // 391
constexpr int BCAP  = 8192;                     // per-bucket capacity (mean 4092, >>6 sigma)
constexpr int BSH   = 13;                       // log2(BCAP)
constexpr int EPB2  = 2048;                     // edges per block (scatter part of k_init)
constexpr int NEB2  = (NE + EPB2 - 1) / EPB2;   // 782
constexpr int H1B   = 1024;                     // h1 blocks
constexpr int WTB   = 128;                      // wt-transpose blocks
constexpr int BDB   = (NV + 255) / 256;         // batch-boundary blocks (391)

typedef short bf16x8 __attribute__((ext_vector_type(8)));
typedef float f32x4 __attribute__((ext_vector_type(4)));

__device__ inline unsigned short f2b(float f) {
    union { float f; unsigned u; } x; x.f = f;
    unsigned r = x.u + 0x7FFF + ((x.u >> 16) & 1);
    return (unsigned short)(r >> 16);
}
__device__ inline float b2f(unsigned short h) {
    union { unsigned u; float f; } x; x.u = (unsigned)h << 16;
    return x.f;
}

// ---------- fused init: scatter | layer-1 H | W transpose | batch boundaries ----------
__global__ __launch_bounds__(256) void k_init(const float* __restrict__ verts,
                                              const float* __restrict__ Win,
                                              const float* __restrict__ bin,
                                              const float* __restrict__ W1,
                                              const float* __restrict__ W2,
                                              const float* __restrict__ W3,
                                              const int* __restrict__ ei,
                                              const int* __restrict__ batch,
                                              int* __restrict__ bcursor,
                                              int* __restrict__ ebuf,
                                              unsigned short* __restrict__ Hb,
                                              unsigned short* __restrict__ Wt,
                                              int* __restrict__ gstart,
                                              int* __restrict__ gend) {
    int t = threadIdx.x;
    int bid = blockIdx.x;
    if (bid < NEB2) {
        // ---- scatter edges into fixed-capacity bucket regions ----
        __shared__ int h[NBUCK];
        __shared__ int lbase[NBUCK];
        for (int i = t; i < NBUCK; i += 256) h[i] = 0;
        __syncthreads();
        int base = bid * EPB2;
        int s[8], d[8], rk[8];
        #pragma unroll
        for (int j = 0; j < 8; ++j) {
            int idx = base + j * 256 + t;
            if (idx < NE) {
                s[j] = ei[idx];
                d[j] = ei[NE + idx];
                rk[j] = atomicAdd(&h[d[j] >> 8], 1);
            } else d[j] = -1;
        }
        __syncthreads();
        for (int i = t; i < NBUCK; i += 256) {
            int c = h[i];
            if (c) lbase[i] = atomicAdd(&bcursor[i], c);
        }
        __syncthreads();
        #pragma unroll
        for (int j = 0; j < 8; ++j)
            if (d[j] >= 0) {
                int b = d[j] >> 8;
                ebuf[(b << BSH) + lbase[b] + rk[j]] = (s[j] << 8) | (d[j] & 255);
            }
        return;
    }
    if (bid < NEB2 + H1B) {
        // ---- layer-1 H from vertices; folds Wc = Win@W1, bc = bin@W1 ----
        __shared__ float Wc[3 * HD];
        __shared__ float bc[HD];
        if (t < HD) {
            float w0 = 0.f, w1 = 0.f, w2 = 0.f, bv = 0.f;
            for (int k = 0; k < HD; ++k) {
                float w = W1[k * HD + t];
                w0 = fmaf(Win[k], w, w0);
                w1 = fmaf(Win[128 + k], w, w1);
                w2 = fmaf(Win[256 + k], w, w2);
                bv = fmaf(bin[k], w, bv);
            }
            Wc[t] = w0; Wc[128 + t] = w1; Wc[256 + t] = w2; bc[t] = bv;
        }
        __syncthreads();
        for (int idx = (bid - NEB2) * 256 + t; idx < NV * HD; idx += H1B * 256) {
            int v = idx >> 7, c = idx & 127;
            float a = verts[v * 3 + 0], b = verts[v * 3 + 1], d = verts[v * 3 + 2];
            Hb[idx] = f2b(bc[c] + a * Wc[c] + b * Wc[128 + c] + d * Wc[256 + c]);
        }
        return;
    }
    if (bid < NEB2 + H1B + WTB) {
        // ---- W2,W3 [k][n] f32 -> Wt [l][n][k] bf16 ----
        int idx = (bid - NEB2 - H1B) * 256 + t;   // 0..32767
        if (idx < 2 * HD * HD) {
            int l = idx >> 14, r = idx & 16383;
            const float* W = (l == 0) ? W2 : W3;
            int n = r >> 7, k = r & 127;
            Wt[(l << 14) + n * HD + k] = f2b(W[k * HD + n]);
        }
        return;
    }
    // ---- batch boundary detection (plain stores; batch is sorted) ----
    int i = (bid - NEB2 - H1B - WTB) * 256 + t;
    if (i < NV) {
        int b = batch[i];
        if (i == 0 || batch[i - 1] != b) gstart[b] = i;
        int bn = (i + 1 < NV) ? batch[i + 1] : -1;
        if (bn != b) gend[b] = i + 1;
    }
}

// ---------- per-bucket CSR: LDS-staged edges, hist -> scan -> fill ----------
__global__ __launch_bounds__(256) void k_bcsr(const int* __restrict__ ebuf,
                                              const int* __restrict__ bcursor,
                                              int* __restrict__ degi,
                                              float* __restrict__ dinv,
                                              int* __restrict__ rowstart,
                                              int* __restrict__ csr) {
    __shared__ int els[BCAP];
    __shared__ int h[DPB];
    __shared__ int sdata[DPB];
    int b = blockIdx.x, t = threadIdx.x, d0 = b * DPB;
    h[t] = 0;
    __syncthreads();
    int e0 = b << BSH;
    int n = bcursor[b];
    for (int i = t; i < n; i += 256) {
        int p = ebuf[e0 + i];
        if (i < BCAP) els[i] = p;
        atomicAdd(&h[p & 255], 1);
    }
    __syncthreads();
    int a = h[t];
    sdata[t] = a;
    __syncthreads();
    for (int off = 1; off < 256; off <<= 1) {
        int v = sdata[t];
        int add = (t >= off) ? sdata[t - off] : 0;
        __syncthreads();
        sdata[t] = v + add;
        __syncthreads();
    }
    int excl = (t == 0) ? 0 : sdata[t - 1];
    int v0 = d0 + t;
    if (v0 < NV) {
        rowstart[v0] = e0 + excl;
        degi[v0] = a;
        dinv[v0] = rsqrtf((float)a + 1.0f);
    }
    h[t] = e0 + excl;
    __syncthreads();
    for (int i = t; i < n; i += 256) {
        int p = (i < BCAP) ? els[i] : ebuf[e0 + i];
        int slot = atomicAdd(&h[p & 255], 1);
        csr[slot] = p >> 8;
    }
}

// ---------- H = X @ W via MFMA; Wt staged in padded LDS; coalesced epilogue ----------
__global__ __launch_bounds__(256) void k_gemm_mfma(const unsigned short* __restrict__ Xb,
                                                   const unsigned short* __restrict__ Wt,
                                                   unsigned short* __restrict__ Hb) {
    __shared__ __align__(16) unsigned short Ws[128 * 132];   // padded rows: bank-spread
    __shared__ __align__(16) unsigned short hs[4][16][136];  // per-wave repack buffer
    int t = threadIdx.x;
    {   // stage Wt -> LDS
        int row = t >> 1;
        int half = (t & 1) << 6;
        const unsigned short* src = Wt + row * HD + half;
        unsigned short* dst = &Ws[row * 132 + half];
        #pragma unroll
        for (int i = 0; i < 8; ++i)
            *(bf16x8*)(dst + i * 8) = *(const bf16x8*)(src + i * 8);
    }
    int wave = t >> 6;
    int lane = t & 63;
    int r = lane & 15;
    int g = lane >> 4;                     // 0..3
    int row0 = blockIdx.x * 64 + wave * 16;
    int arow = row0 + r;
    bool valid = arow < NV;

    bf16x8 afrag[4];
    const unsigned short* xp = Xb + (size_t)arow * HD + g * 8;
    #pragma unroll
    for (int ks = 0; ks < 4; ++ks) {
        if (valid) afrag[ks] = *(const bf16x8*)(xp + ks * 32);
        else       afrag[ks] = bf16x8{0, 0, 0, 0, 0, 0, 0, 0};
    }
    __syncthreads();

    #pragma unroll
    for (int nt = 0; nt < 8; ++nt) {
        f32x4 acc = {0.f, 0.f, 0.f, 0.f};
        #pragma unroll
        for (int ks = 0; ks < 4; ++ks) {
            bf16x8 bfrag = *(const bf16x8*)&Ws[(nt * 16 + r) * 132 + g * 8 + ks * 32];
            acc = __builtin_amdgcn_mfma_f32_16x16x32_bf16(afrag[ks], bfrag, acc, 0, 0, 0);
        }
        #pragma unroll
        for (int j = 0; j < 4; ++j)
            hs[wave][g * 4 + j][nt * 16 + r] = f2b(acc[j]);
    }
    int row = lane >> 2;
    int grow = row0 + row;
    #pragma unroll
    for (int k = 0; k < 4; ++k) {
        int c = (lane & 3) + k * 4;      // chunk 0..15 (8 shorts each)
        bf16x8 val = *(const bf16x8*)&hs[wave][row][c * 8];
        if (grow < NV)
            *(bf16x8*)(Hb + (size_t)grow * HD + c * 8) = val;
    }
}

// ---------- aggregate: one wave per dst, quarter-waves over edges, bf16x8 rows ----------
__global__ __launch_bounds__(256) void k_agg(const unsigned short* __restrict__ H,
                                             const float* __restrict__ dinv,
                                             const int* __restrict__ rowstart,
                                             const int* __restrict__ degi,
                                             const int* __restrict__ csr_src,
                                             const float* __restrict__ bias,
                                             unsigned short* __restrict__ Xo) {
    int gtid = blockIdx.x * 256 + threadIdx.x;
    int v = gtid >> 6;
    if (v >= NV) return;
    int lane = threadIdx.x & 63;
    int q = lane >> 4;        // quarter 0..3: edges q, q+4, ...
    int l4 = lane & 15;       // col group: cols l4*8 .. l4*8+7
    float di = dinv[v];
    int rs = rowstart[v], len = degi[v];
    float a[8];
    if (q == 0) {
        float sc = di * di;
        bf16x8 hv = *(const bf16x8*)(H + (size_t)v * HD + l4 * 8);
        #pragma unroll
        for (int jj = 0; jj < 8; ++jj) a[jj] = b2f((unsigned short)hv[jj]) * sc;
    } else {
        #pragma unroll
        for (int jj = 0; jj < 8; ++jj) a[jj] = 0.f;
    }
    int cnt = (len - q + 3) >> 2;   // edges this quarter handles
    int idx = rs + q;
    int j = 0;
    for (; j + 1 < cnt; j += 2) {
        int s0 = csr_src[idx], s1 = csr_src[idx + 4];
        idx += 8;
        float w0 = dinv[s0] * di, w1 = dinv[s1] * di;
        bf16x8 h0 = *(const bf16x8*)(H + (size_t)s0 * HD + l4 * 8);
        bf16x8 h1 = *(const bf16x8*)(H + (size_t)s1 * HD + l4 * 8);
        #pragma unroll
        for (int jj = 0; jj < 8; ++jj) {
            a[jj] = fmaf(b2f((unsigned short)h0[jj]), w0, a[jj]);
            a[jj] = fmaf(b2f((unsigned short)h1[jj]), w1, a[jj]);
        }
    }
    if (j < cnt) {
        int s0 = csr_src[idx];
        float w0 = dinv[s0] * di;
        bf16x8 h0 = *(const bf16x8*)(H + (size_t)s0 * HD + l4 * 8);
        #pragma unroll
        for (int jj = 0; jj < 8; ++jj)
            a[jj] = fmaf(b2f((unsigned short)h0[jj]), w0, a[jj]);
    }
    // reduce across quarters (lanes l4, l4+16, l4+32, l4+48)
    #pragma unroll
    for (int jj = 0; jj < 8; ++jj) {
        a[jj] += __shfl_xor(a[jj], 16);
        a[jj] += __shfl_xor(a[jj], 32);
    }
    if (q == 0) {
        bf16x8 ov;
        #pragma unroll
        for (int jj = 0; jj < 8; ++jj)
            ov[jj] = (short)f2b(fmaxf(a[jj] + bias[l4 * 8 + jj], 0.f));
        *(bf16x8*)(Xo + (size_t)v * HD + l4 * 8) = ov;
    }
}

// ---------- mean pool: vectorized bf16x8 loads; LDS accumulate; few global atomics ----------
__global__ __launch_bounds__(256) void k_pool(const unsigned short* __restrict__ X,
                                              const int* __restrict__ batch,
                                              float* __restrict__ pool) {
    constexpr int CHUNK = (NV + 2047) / 2048;  // 49
    __shared__ float lp[2][HD];
    __shared__ int binfo[2];
    int t = threadIdx.x;
    int v0 = blockIdx.x * CHUNK;
    if (v0 >= NV) return;
    int vend = min(v0 + CHUNK, NV);
    if (t < 2 * HD) ((float*)lp)[t] = 0.f;
    if (t == 0) { binfo[0] = batch[v0]; binfo[1] = batch[vend - 1]; }
    __syncthreads();
    int b0 = binfo[0], b1 = binfo[1];
    int cg = t & 15;      // col group (8 cols)
    int ro = t >> 4;      // 0..15 row offset
    if (b1 - b0 <= 1) {
        float a0[8] = {}, a1[8] = {};
        for (int v = v0 + ro; v < vend; v += 16) {
            bf16x8 x = *(const bf16x8*)(X + (size_t)v * HD + cg * 8);
            if (batch[v] == b0) {
                #pragma unroll
                for (int jj = 0; jj < 8; ++jj) a0[jj] += b2f((unsigned short)x[jj]);
            } else {
                #pragma unroll
                for (int jj = 0; jj < 8; ++jj) a1[jj] += b2f((unsigned short)x[jj]);
            }
        }
        #pragma unroll
        for (int jj = 0; jj < 8; ++jj) {
            atomicAdd(&lp[0][cg * 8 + jj], a0[jj]);
            if (b1 != b0) atomicAdd(&lp[1][cg * 8 + jj], a1[jj]);
        }
        __syncthreads();
        int slot = t >> 7, col = t & 127;
        if (slot == 0 || b1 != b0)
            atomicAdd(&pool[(slot ? b1 : b0) * HD + col], lp[slot][col]);
    } else {
        float a[8] = {};
        int cur = -1;
        for (int v = v0 + ro; v < vend; v += 16) {
            int bb = batch[v];
            if (bb != cur) {
                if (cur >= 0) {
                    #pragma unroll
                    for (int jj = 0; jj < 8; ++jj) {
                        atomicAdd(&pool[cur * HD + cg * 8 + jj], a[jj]);
                        a[jj] = 0.f;
                    }
                }
                cur = bb;
            }
            bf16x8 x = *(const bf16x8*)(X + (size_t)v * HD + cg * 8);
            #pragma unroll
            for (int jj = 0; jj < 8; ++jj) a[jj] += b2f((unsigned short)x[jj]);
        }
        if (cur >= 0) {
            #pragma unroll
            for (int jj = 0; jj < 8; ++jj)
                atomicAdd(&pool[cur * HD + cg * 8 + jj], a[jj]);
        }
    }
}

// ---------- final: mean, linear, layernorm; one block per graph ----------
__global__ __launch_bounds__(256) void k_out(const float* __restrict__ pool,
                                             const int* __restrict__ gstart,
                                             const int* __restrict__ gend,
                                             const float* __restrict__ Wout,
                                             const float* __restrict__ bout,
                                             const float* __restrict__ gamma,
                                             const float* __restrict__ beta,
                                             float* __restrict__ out) {
    __shared__ float ps[HD];
    __shared__ float red[DM];
    int g = blockIdx.x, t = threadIdx.x;
    if (t < HD) {
        float cn = fmaxf((float)(gend[g] - gstart[g]), 1.0f);
        ps[t] = pool[g * HD + t] / cn;
    }
    __syncthreads();
    float acc = bout[t];
    #pragma unroll 8
    for (int k = 0; k < HD; ++k) acc = fmaf(ps[k], Wout[k * DM + t], acc);
    red[t] = acc; __syncthreads();
    for (int s2 = 128; s2 > 0; s2 >>= 1) {
        if (t < s2) red[t] += red[t + s2];
        __syncthreads();
    }
    float mu = red[0] * (1.0f / DM);
    __syncthreads();
    float d = acc - mu;
    red[t] = d * d; __syncthreads();
    for (int s2 = 128; s2 > 0; s2 >>= 1) {
        if (t < s2) red[t] += red[t + s2];
        __syncthreads();
    }
    float var = red[0] * (1.0f / DM);
    out[g * DM + t] = d * rsqrtf(var + EPSLN) * gamma[t] + beta[t];
}

extern "C" void kernel_launch(void* const* d_in, const int* in_sizes, int n_in,
                              void* d_out, int out_size, void* d_ws, size_t ws_size,
                              hipStream_t stream) {
    const float* verts = (const float*)d_in[0];
    const int*   ei    = (const int*)d_in[1];
    const int*   batch = (const int*)d_in[2];
    const float* Win   = (const float*)d_in[3];
    const float* bin   = (const float*)d_in[4];
    const float* W1    = (const float*)d_in[5];
    const float* b1    = (const float*)d_in[6];
    const float* W2    = (const float*)d_in[7];
    const float* b2    = (const float*)d_in[8];
    const float* W3    = (const float*)d_in[9];
    const float* b3    = (const float*)d_in[10];
    const float* Wout  = (const float*)d_in[11];
    const float* bout  = (const float*)d_in[12];
    const float* gamma = (const float*)d_in[13];
    const float* beta  = (const float*)d_in[14];
    float* out = (float*)d_out;

    char* wp = (char*)d_ws;
    auto alloc = [&](size_t bytes) -> char* {
        char* p = wp;
        wp += (bytes + 255) & ~(size_t)255;
        return p;
    };
    unsigned short* bufA = (unsigned short*)alloc((size_t)NV * HD * 2);
    unsigned short* bufB = (unsigned short*)alloc((size_t)NV * HD * 2);
    unsigned short* Wt   = (unsigned short*)alloc((size_t)2 * HD * HD * 2);
    int*   degi     = (int*)alloc((size_t)NV * 4);
    float* dinv     = (float*)alloc((size_t)NV * 4);
    int*   rowstart = (int*)alloc((size_t)NV * 4);
    int*   csr      = (int*)alloc((size_t)NBUCK * BCAP * 4);
    int*   ebuf     = (int*)alloc((size_t)NBUCK * BCAP * 4);
    // contiguous zero region: bcursor | pool | gstart | gend
    size_t zb_cursor = ((size_t)NBUCK * 4 + 255) & ~(size_t)255;
    size_t zb_pool   = (size_t)NB * HD * 4;
    size_t zb_tot    = zb_cursor + zb_pool + 1024;
    char*  zblock   = alloc(zb_tot);
    int*   bcursor  = (int*)zblock;
    float* pool     = (float*)(zblock + zb_cursor);
    int*   gstart   = (int*)(zblock + zb_cursor + zb_pool);
    int*   gend     = (int*)(zblock + zb_cursor + zb_pool + 512);

    hipMemsetAsync(zblock, 0, zb_tot, stream);

    // fused init: edge scatter + layer-1 H + W transpose + batch boundaries
    k_init<<<NEB2 + H1B + WTB + BDB, 256, 0, stream>>>(verts, Win, bin, W1, W2, W3,
                                                       ei, batch, bcursor, ebuf,
                                                       bufA, Wt, gstart, gend);
    // per-bucket CSR build (LDS-staged)
    k_bcsr<<<NBUCK, 256, 0, stream>>>(ebuf, bcursor, degi, dinv, rowstart, csr);

    int aggrid = (int)(((size_t)NV * 64 + 255) / 256);
    // layer 1
    k_agg<<<aggrid, 256, 0, stream>>>(bufA, dinv, rowstart, degi, csr, b1, bufB);
    k_gemm_mfma<<<(NV + 63) / 64, 256, 0, stream>>>(bufB, Wt, bufA);
    // layer 2
    k_agg<<<aggrid, 256, 0, stream>>>(bufA, dinv, rowstart, degi, csr, b2, bufB);
    k_gemm_mfma<<<(NV + 63) / 64, 256, 0, stream>>>(bufB, Wt + (size_t)HD * HD, bufA);
    // layer 3
    k_agg<<<aggrid, 256, 0, stream>>>(bufA, dinv, rowstart, degi, csr, b3, bufB);

    k_pool<<<2048, 256, 0, stream>>>(bufB, batch, pool);
    k_out<<<NB, 256, 0, stream>>>(pool, gstart, gend, Wout, bout, gamma, beta, out);
}

// Round 16
// 329.083 us; speedup vs baseline: 4.7341x; 1.0342x over previous
//
#include <hip/hip_runtime.h>

// Problem constants (match reference setup_inputs)
constexpr int NV = 100000;   // vertices
constexpr int NE = 1600000;  // directed edges
constexpr int NB = 64;       // graphs
constexpr int HD = 128;      // hidden
constexpr int DM = 256;      // out dim
#define EPSLN 1e-5f

// CSR bucketing (fixed-capacity bucket regions)
constexpr int DPB   = 256;                      // dsts per bucket
constexpr int NBUCK = (NV + DPB - 1) / DPB;     // 391
constexpr int BCAP  = 8192;                     // per-bucket capacity (mean 4092, >>6 sigma)
constexpr int BSH   = 13;                       // log2(BCAP)
constexpr int EPB3  = 4096;                     // edges per block (scatter part of k_init)
constexpr int NEB3  = (NE + EPB3 - 1) / EPB3;   // 391
constexpr int H1B   = 1024;                     // h1 blocks
constexpr int WTB   = 128;                      // wt-transpose blocks
constexpr int BDB   = (NV + 255) / 256;         // batch-boundary blocks (391)

typedef short bf16x8 __attribute__((ext_vector_type(8)));
typedef float f32x4 __attribute__((ext_vector_type(4)));

__device__ inline unsigned short f2b(float f) {
    union { float f; unsigned u; } x; x.f = f;
    unsigned r = x.u + 0x7FFF + ((x.u >> 16) & 1);
    return (unsigned short)(r >> 16);
}
__device__ inline float b2f(unsigned short h) {
    union { unsigned u; float f; } x; x.u = (unsigned)h << 16;
    return x.f;
}

// ---------- fused init: scatter | layer-1 H | W transpose | boundaries + pool-zero ----------
__global__ __launch_bounds__(256) void k_init(const float* __restrict__ verts,
                                              const float* __restrict__ Win,
                                              const float* __restrict__ bin,
                                              const float* __restrict__ W1,
                                              const float* __restrict__ W2,
                                              const float* __restrict__ W3,
                                              const int* __restrict__ ei,
                                              const int* __restrict__ batch,
                                              int* __restrict__ bcursor,
                                              int* __restrict__ ebuf,
                                              unsigned short* __restrict__ Hb,
                                              unsigned short* __restrict__ Wt,
                                              int* __restrict__ gstart,
                                              int* __restrict__ gend,
                                              float* __restrict__ pool) {
    int t = threadIdx.x;
    int bid = blockIdx.x;
    if (bid < NEB3) {
        // ---- scatter edges into fixed-capacity bucket regions ----
        __shared__ int h[NBUCK];
        __shared__ int lbase[NBUCK];
        for (int i = t; i < NBUCK; i += 256) h[i] = 0;
        __syncthreads();
        int base = bid * EPB3;
        int s[16], d[16], rk[16];
        #pragma unroll
        for (int j = 0; j < 16; ++j) {
            int idx = base + j * 256 + t;
            if (idx < NE) {
                s[j] = ei[idx];
                d[j] = ei[NE + idx];
                rk[j] = atomicAdd(&h[d[j] >> 8], 1);
            } else d[j] = -1;
        }
        __syncthreads();
        for (int i = t; i < NBUCK; i += 256) {
            int c = h[i];
            if (c) lbase[i] = atomicAdd(&bcursor[i], c);
        }
        __syncthreads();
        #pragma unroll
        for (int j = 0; j < 16; ++j)
            if (d[j] >= 0) {
                int b = d[j] >> 8;
                ebuf[(b << BSH) + lbase[b] + rk[j]] = (s[j] << 8) | (d[j] & 255);
            }
        return;
    }
    if (bid < NEB3 + H1B) {
        // ---- layer-1 H from vertices; folds Wc = Win@W1, bc = bin@W1 ----
        __shared__ float Wc[3 * HD];
        __shared__ float bc[HD];
        if (t < HD) {
            float w0 = 0.f, w1 = 0.f, w2 = 0.f, bv = 0.f;
            for (int k = 0; k < HD; ++k) {
                float w = W1[k * HD + t];
                w0 = fmaf(Win[k], w, w0);
                w1 = fmaf(Win[128 + k], w, w1);
                w2 = fmaf(Win[256 + k], w, w2);
                bv = fmaf(bin[k], w, bv);
            }
            Wc[t] = w0; Wc[128 + t] = w1; Wc[256 + t] = w2; bc[t] = bv;
        }
        __syncthreads();
        for (int idx = (bid - NEB3) * 256 + t; idx < NV * HD; idx += H1B * 256) {
            int v = idx >> 7, c = idx & 127;
            float a = verts[v * 3 + 0], b = verts[v * 3 + 1], d = verts[v * 3 + 2];
            Hb[idx] = f2b(bc[c] + a * Wc[c] + b * Wc[128 + c] + d * Wc[256 + c]);
        }
        return;
    }
    if (bid < NEB3 + H1B + WTB) {
        // ---- W2,W3 [k][n] f32 -> Wt [l][n][k] bf16 ----
        int idx = (bid - NEB3 - H1B) * 256 + t;   // 0..32767
        if (idx < 2 * HD * HD) {
            int l = idx >> 14, r = idx & 16383;
            const float* W = (l == 0) ? W2 : W3;
            int n = r >> 7, k = r & 127;
            Wt[(l << 14) + n * HD + k] = f2b(W[k * HD + n]);
        }
        return;
    }
    // ---- batch boundary detection + pool zeroing ----
    int i = (bid - NEB3 - H1B - WTB) * 256 + t;
    if (i < NB * HD) pool[i] = 0.f;
    if (i < NV) {
        int b = batch[i];
        if (i == 0 || batch[i - 1] != b) gstart[b] = i;
        int bn = (i + 1 < NV) ? batch[i + 1] : -1;
        if (bn != b) gend[b] = i + 1;
    }
}

// ---------- per-bucket CSR: LDS-staged edges, hist -> scan -> fill ----------
__global__ __launch_bounds__(256) void k_bcsr(const int* __restrict__ ebuf,
                                              const int* __restrict__ bcursor,
                                              int* __restrict__ degi,
                                              float* __restrict__ dinv,
                                              int* __restrict__ rowstart,
                                              int* __restrict__ csr) {
    __shared__ int els[BCAP];
    __shared__ int h[DPB];
    __shared__ int sdata[DPB];
    int b = blockIdx.x, t = threadIdx.x, d0 = b * DPB;
    h[t] = 0;
    __syncthreads();
    int e0 = b << BSH;
    int n = bcursor[b];
    for (int i = t; i < n; i += 256) {
        int p = ebuf[e0 + i];
        if (i < BCAP) els[i] = p;
        atomicAdd(&h[p & 255], 1);
    }
    __syncthreads();
    int a = h[t];
    sdata[t] = a;
    __syncthreads();
    for (int off = 1; off < 256; off <<= 1) {
        int v = sdata[t];
        int add = (t >= off) ? sdata[t - off] : 0;
        __syncthreads();
        sdata[t] = v + add;
        __syncthreads();
    }
    int excl = (t == 0) ? 0 : sdata[t - 1];
    int v0 = d0 + t;
    if (v0 < NV) {
        rowstart[v0] = e0 + excl;
        degi[v0] = a;
        dinv[v0] = rsqrtf((float)a + 1.0f);
    }
    h[t] = e0 + excl;
    __syncthreads();
    for (int i = t; i < n; i += 256) {
        int p = (i < BCAP) ? els[i] : ebuf[e0 + i];
        int slot = atomicAdd(&h[p & 255], 1);
        csr[slot] = p >> 8;
    }
}

// ---------- H = X @ W via MFMA; Ws staged + reused as repack buffer (34 KB LDS) ----------
__global__ __launch_bounds__(256) void k_gemm_mfma(const unsigned short* __restrict__ Xb,
                                                   const unsigned short* __restrict__ Wt,
                                                   unsigned short* __restrict__ Hb) {
    __shared__ __align__(16) unsigned short Ws[128 * 132];   // 33.8 KB; later reused for repack
    int t = threadIdx.x;
    {   // stage Wt -> LDS
        int row = t >> 1;
        int half = (t & 1) << 6;
        const unsigned short* src = Wt + row * HD + half;
        unsigned short* dst = &Ws[row * 132 + half];
        #pragma unroll
        for (int i = 0; i < 8; ++i)
            *(bf16x8*)(dst + i * 8) = *(const bf16x8*)(src + i * 8);
    }
    int wave = t >> 6;
    int lane = t & 63;
    int r = lane & 15;
    int g = lane >> 4;                     // 0..3
    int row0 = blockIdx.x * 64 + wave * 16;
    int arow = row0 + r;
    bool valid = arow < NV;

    bf16x8 afrag[4];
    const unsigned short* xp = Xb + (size_t)arow * HD + g * 8;
    #pragma unroll
    for (int ks = 0; ks < 4; ++ks) {
        if (valid) afrag[ks] = *(const bf16x8*)(xp + ks * 32);
        else       afrag[ks] = bf16x8{0, 0, 0, 0, 0, 0, 0, 0};
    }
    __syncthreads();

    f32x4 acc[8];
    #pragma unroll
    for (int nt = 0; nt < 8; ++nt) {
        acc[nt] = f32x4{0.f, 0.f, 0.f, 0.f};
        #pragma unroll
        for (int ks = 0; ks < 4; ++ks) {
            bf16x8 bfrag = *(const bf16x8*)&Ws[(nt * 16 + r) * 132 + g * 8 + ks * 32];
            acc[nt] = __builtin_amdgcn_mfma_f32_16x16x32_bf16(afrag[ks], bfrag, acc[nt], 0, 0, 0);
        }
    }
    __syncthreads();   // all waves done reading Ws; safe to reuse as repack buffer
    // C/D: col = lane&15 (=r), row = g*4 + j -> per-wave region of Ws, then 16B stores
    unsigned short* hsw = Ws + wave * 16 * 136;
    #pragma unroll
    for (int nt = 0; nt < 8; ++nt)
        #pragma unroll
        for (int j = 0; j < 4; ++j)
            hsw[(g * 4 + j) * 136 + nt * 16 + r] = f2b(acc[nt][j]);
    int row = lane >> 2;
    int grow = row0 + row;
    #pragma unroll
    for (int k = 0; k < 4; ++k) {
        int c = (lane & 3) + k * 4;      // chunk 0..15 (8 shorts each)
        bf16x8 val = *(const bf16x8*)&hsw[row * 136 + c * 8];
        if (grow < NV)
            *(bf16x8*)(Hb + (size_t)grow * HD + c * 8) = val;
    }
}

// ---------- aggregate: one wave per dst, quarter-waves over edges, bf16x8 rows ----------
__global__ __launch_bounds__(256) void k_agg(const unsigned short* __restrict__ H,
                                             const float* __restrict__ dinv,
                                             const int* __restrict__ rowstart,
                                             const int* __restrict__ degi,
                                             const int* __restrict__ csr_src,
                                             const float* __restrict__ bias,
                                             unsigned short* __restrict__ Xo) {
    int gtid = blockIdx.x * 256 + threadIdx.x;
    int v = gtid >> 6;
    if (v >= NV) return;
    int lane = threadIdx.x & 63;
    int q = lane >> 4;        // quarter 0..3: edges q, q+4, ...
    int l4 = lane & 15;       // col group: cols l4*8 .. l4*8+7
    float di = dinv[v];
    int rs = rowstart[v], len = degi[v];
    float a[8];
    if (q == 0) {
        float sc = di * di;
        bf16x8 hv = *(const bf16x8*)(H + (size_t)v * HD + l4 * 8);
        #pragma unroll
        for (int jj = 0; jj < 8; ++jj) a[jj] = b2f((unsigned short)hv[jj]) * sc;
    } else {
        #pragma unroll
        for (int jj = 0; jj < 8; ++jj) a[jj] = 0.f;
    }
    int cnt = (len - q + 3) >> 2;   // edges this quarter handles
    int idx = rs + q;
    int j = 0;
    for (; j + 1 < cnt; j += 2) {
        int s0 = csr_src[idx], s1 = csr_src[idx + 4];
        idx += 8;
        float w0 = dinv[s0] * di, w1 = dinv[s1] * di;
        bf16x8 h0 = *(const bf16x8*)(H + (size_t)s0 * HD + l4 * 8);
        bf16x8 h1 = *(const bf16x8*)(H + (size_t)s1 * HD + l4 * 8);
        #pragma unroll
        for (int jj = 0; jj < 8; ++jj) {
            a[jj] = fmaf(b2f((unsigned short)h0[jj]), w0, a[jj]);
            a[jj] = fmaf(b2f((unsigned short)h1[jj]), w1, a[jj]);
        }
    }
    if (j < cnt) {
        int s0 = csr_src[idx];
        float w0 = dinv[s0] * di;
        bf16x8 h0 = *(const bf16x8*)(H + (size_t)s0 * HD + l4 * 8);
        #pragma unroll
        for (int jj = 0; jj < 8; ++jj)
            a[jj] = fmaf(b2f((unsigned short)h0[jj]), w0, a[jj]);
    }
    // reduce across quarters (lanes l4, l4+16, l4+32, l4+48)
    #pragma unroll
    for (int jj = 0; jj < 8; ++jj) {
        a[jj] += __shfl_xor(a[jj], 16);
        a[jj] += __shfl_xor(a[jj], 32);
    }
    if (q == 0) {
        bf16x8 ov;
        #pragma unroll
        for (int jj = 0; jj < 8; ++jj)
            ov[jj] = (short)f2b(fmaxf(a[jj] + bias[l4 * 8 + jj], 0.f));
        *(bf16x8*)(Xo + (size_t)v * HD + l4 * 8) = ov;
    }
}

// ---------- mean pool: vectorized bf16x8 loads; LDS accumulate; few global atomics ----------
__global__ __launch_bounds__(256) void k_pool(const unsigned short* __restrict__ X,
                                              const int* __restrict__ batch,
                                              float* __restrict__ pool) {
    constexpr int CHUNK = (NV + 2047) / 2048;  // 49
    __shared__ float lp[2][HD];
    __shared__ int binfo[2];
    int t = threadIdx.x;
    int v0 = blockIdx.x * CHUNK;
    if (v0 >= NV) return;
    int vend = min(v0 + CHUNK, NV);
    if (t < 2 * HD) ((float*)lp)[t] = 0.f;
    if (t == 0) { binfo[0] = batch[v0]; binfo[1] = batch[vend - 1]; }
    __syncthreads();
    int b0 = binfo[0], b1 = binfo[1];
    int cg = t & 15;      // col group (8 cols)
    int ro = t >> 4;      // 0..15 row offset
    if (b1 - b0 <= 1) {
        float a0[8] = {}, a1[8] = {};
        for (int v = v0 + ro; v < vend; v += 16) {
            bf16x8 x = *(const bf16x8*)(X + (size_t)v * HD + cg * 8);
            if (batch[v] == b0) {
                #pragma unroll
                for (int jj = 0; jj < 8; ++jj) a0[jj] += b2f((unsigned short)x[jj]);
            } else {
                #pragma unroll
                for (int jj = 0; jj < 8; ++jj) a1[jj] += b2f((unsigned short)x[jj]);
            }
        }
        #pragma unroll
        for (int jj = 0; jj < 8; ++jj) {
            atomicAdd(&lp[0][cg * 8 + jj], a0[jj]);
            if (b1 != b0) atomicAdd(&lp[1][cg * 8 + jj], a1[jj]);
        }
        __syncthreads();
        int slot = t >> 7, col = t & 127;
        if (slot == 0 || b1 != b0)
            atomicAdd(&pool[(slot ? b1 : b0) * HD + col], lp[slot][col]);
    } else {
        float a[8] = {};
        int cur = -1;
        for (int v = v0 + ro; v < vend; v += 16) {
            int bb = batch[v];
            if (bb != cur) {
                if (cur >= 0) {
                    #pragma unroll
                    for (int jj = 0; jj < 8; ++jj) {
                        atomicAdd(&pool[cur * HD + cg * 8 + jj], a[jj]);
                        a[jj] = 0.f;
                    }
                }
                cur = bb;
            }
            bf16x8 x = *(const bf16x8*)(X + (size_t)v * HD + cg * 8);
            #pragma unroll
            for (int jj = 0; jj < 8; ++jj) a[jj] += b2f((unsigned short)x[jj]);
        }
        if (cur >= 0) {
            #pragma unroll
            for (int jj = 0; jj < 8; ++jj)
                atomicAdd(&pool[cur * HD + cg * 8 + jj], a[jj]);
        }
    }
}

// ---------- final: mean, linear, layernorm; one block per graph ----------
__global__ __launch_bounds__(256) void k_out(const float* __restrict__ pool,
                                             const int* __restrict__ gstart,
                                             const int* __restrict__ gend,
                                             const float* __restrict__ Wout,
                                             const float* __restrict__ bout,
                                             const float* __restrict__ gamma,
                                             const float* __restrict__ beta,
                                             float* __restrict__ out) {
    __shared__ float ps[HD];
    __shared__ float red[DM];
    int g = blockIdx.x, t = threadIdx.x;
    if (t < HD) {
        float cn = fmaxf((float)(gend[g] - gstart[g]), 1.0f);
        ps[t] = pool[g * HD + t] / cn;
    }
    __syncthreads();
    float acc = bout[t];
    #pragma unroll 8
    for (int k = 0; k < HD; ++k) acc = fmaf(ps[k], Wout[k * DM + t], acc);
    red[t] = acc; __syncthreads();
    for (int s2 = 128; s2 > 0; s2 >>= 1) {
        if (t < s2) red[t] += red[t + s2];
        __syncthreads();
    }
    float mu = red[0] * (1.0f / DM);
    __syncthreads();
    float d = acc - mu;
    red[t] = d * d; __syncthreads();
    for (int s2 = 128; s2 > 0; s2 >>= 1) {
        if (t < s2) red[t] += red[t + s2];
        __syncthreads();
    }
    float var = red[0] * (1.0f / DM);
    out[g * DM + t] = d * rsqrtf(var + EPSLN) * gamma[t] + beta[t];
}

extern "C" void kernel_launch(void* const* d_in, const int* in_sizes, int n_in,
                              void* d_out, int out_size, void* d_ws, size_t ws_size,
                              hipStream_t stream) {
    const float* verts = (const float*)d_in[0];
    const int*   ei    = (const int*)d_in[1];
    const int*   batch = (const int*)d_in[2];
    const float* Win   = (const float*)d_in[3];
    const float* bin   = (const float*)d_in[4];
    const float* W1    = (const float*)d_in[5];
    const float* b1    = (const float*)d_in[6];
    const float* W2    = (const float*)d_in[7];
    const float* b2    = (const float*)d_in[8];
    const float* W3    = (const float*)d_in[9];
    const float* b3    = (const float*)d_in[10];
    const float* Wout  = (const float*)d_in[11];
    const float* bout  = (const float*)d_in[12];
    const float* gamma = (const float*)d_in[13];
    const float* beta  = (const float*)d_in[14];
    float* out = (float*)d_out;

    char* wp = (char*)d_ws;
    auto alloc = [&](size_t bytes) -> char* {
        char* p = wp;
        wp += (bytes + 255) & ~(size_t)255;
        return p;
    };
    unsigned short* bufA = (unsigned short*)alloc((size_t)NV * HD * 2);
    unsigned short* bufB = (unsigned short*)alloc((size_t)NV * HD * 2);
    unsigned short* Wt   = (unsigned short*)alloc((size_t)2 * HD * HD * 2);
    int*   degi     = (int*)alloc((size_t)NV * 4);
    float* dinv     = (float*)alloc((size_t)NV * 4);
    int*   rowstart = (int*)alloc((size_t)NV * 4);
    int*   csr      = (int*)alloc((size_t)NBUCK * BCAP * 4);
    int*   ebuf     = (int*)alloc((size_t)NBUCK * BCAP * 4);
    float* pool     = (float*)alloc((size_t)NB * HD * 4);
    // small zero region: bcursor | gstart | gend
    size_t zb_cursor = ((size_t)NBUCK * 4 + 255) & ~(size_t)255;
    size_t zb_tot    = zb_cursor + 1024;
    char*  zblock   = alloc(zb_tot);
    int*   bcursor  = (int*)zblock;
    int*   gstart   = (int*)(zblock + zb_cursor);
    int*   gend     = (int*)(zblock + zb_cursor + 512);

    hipMemsetAsync(zblock, 0, zb_tot, stream);

    // fused init: edge scatter + layer-1 H + W transpose + boundaries/pool-zero
    k_init<<<NEB3 + H1B + WTB + BDB, 256, 0, stream>>>(verts, Win, bin, W1, W2, W3,
                                                       ei, batch, bcursor, ebuf,
                                                       bufA, Wt, gstart, gend, pool);
    // per-bucket CSR build (LDS-staged)
    k_bcsr<<<NBUCK, 256, 0, stream>>>(ebuf, bcursor, degi, dinv, rowstart, csr);

    int aggrid = (int)(((size_t)NV * 64 + 255) / 256);
    // layer 1
    k_agg<<<aggrid, 256, 0, stream>>>(bufA, dinv, rowstart, degi, csr, b1, bufB);
    k_gemm_mfma<<<(NV + 63) / 64, 256, 0, stream>>>(bufB, Wt, bufA);
    // layer 2
    k_agg<<<aggrid, 256, 0, stream>>>(bufA, dinv, rowstart, degi, csr, b2, bufB);
    k_gemm_mfma<<<(NV + 63) / 64, 256, 0, stream>>>(bufB, Wt + (size_t)HD * HD, bufA);
    // layer 3
    k_agg<<<aggrid, 256, 0, stream>>>(bufA, dinv, rowstart, degi, csr, b3, bufB);

    k_pool<<<2048, 256, 0, stream>>>(bufB, batch, pool);
    k_out<<<NB, 256, 0, stream>>>(pool, gstart, gend, Wout, bout, gamma, beta, out);
}

// Round 17
// 321.967 us; speedup vs baseline: 4.8388x; 1.0221x over previous
//
#include <hip/hip_runtime.h>

// Problem constants (match reference setup_inputs)
constexpr int NV = 100000;   // vertices
constexpr int NE = 1600000;  // directed edges
constexpr int NB = 64;       // graphs
constexpr int HD = 128;      // hidden
constexpr int DM = 256;      // out dim
#define EPSLN 1e-5f

// CSR bucketing (fixed-capacity bucket regions)
constexpr int DPB   = 256;                      // dsts per bucket
constexpr int NBUCK = (NV + DPB - 1) / DPB;     // 391
constexpr int BCAP  = 8192;                     // per-bucket capacity (mean 4092, >>6 sigma)
constexpr int BSH   = 13;                       // log2(BCAP)
constexpr int EPB3  = 4096;                     // edges per block (scatter part of k_init)
constexpr int NEB3  = (NE + EPB3 - 1) / EPB3;   // 391
constexpr int H1B   = 1024;                     // h1 blocks
constexpr int WTB   = 128;                      // wt-transpose blocks
constexpr int BDB   = (NV + 255) / 256;         // batch-boundary blocks (391)

typedef short bf16x8 __attribute__((ext_vector_type(8)));
typedef float f32x4 __attribute__((ext_vector_type(4)));

__device__ inline unsigned short f2b(float f) {
    union { float f; unsigned u; } x; x.f = f;
    unsigned r = x.u + 0x7FFF + ((x.u >> 16) & 1);
    return (unsigned short)(r >> 16);
}
__device__ inline float b2f(unsigned short h) {
    union { unsigned u; float f; } x; x.u = (unsigned)h << 16;
    return x.f;
}

// ---------- fused init: scatter | layer-1 H | W transpose | boundaries + pool-zero ----------
__global__ __launch_bounds__(256) void k_init(const float* __restrict__ verts,
                                              const float* __restrict__ Win,
                                              const float* __restrict__ bin,
                                              const float* __restrict__ W1,
                                              const float* __restrict__ W2,
                                              const float* __restrict__ W3,
                                              const int* __restrict__ ei,
                                              const int* __restrict__ batch,
                                              int* __restrict__ bcursor,
                                              int* __restrict__ ebuf,
                                              unsigned short* __restrict__ Hb,
                                              unsigned short* __restrict__ Wt,
                                              int* __restrict__ gstart,
                                              int* __restrict__ gend,
                                              float* __restrict__ pool) {
    int t = threadIdx.x;
    int bid = blockIdx.x;
    if (bid < NEB3) {
        // ---- scatter edges into fixed-capacity bucket regions ----
        __shared__ int h[NBUCK];
        __shared__ int lbase[NBUCK];
        for (int i = t; i < NBUCK; i += 256) h[i] = 0;
        __syncthreads();
        int base = bid * EPB3;
        int s[16], d[16], rk[16];
        #pragma unroll
        for (int j = 0; j < 16; ++j) {
            int idx = base + j * 256 + t;
            if (idx < NE) {
                s[j] = ei[idx];
                d[j] = ei[NE + idx];
                rk[j] = atomicAdd(&h[d[j] >> 8], 1);
            } else d[j] = -1;
        }
        __syncthreads();
        for (int i = t; i < NBUCK; i += 256) {
            int c = h[i];
            if (c) lbase[i] = atomicAdd(&bcursor[i], c);
        }
        __syncthreads();
        #pragma unroll
        for (int j = 0; j < 16; ++j)
            if (d[j] >= 0) {
                int b = d[j] >> 8;
                ebuf[(b << BSH) + lbase[b] + rk[j]] = (s[j] << 8) | (d[j] & 255);
            }
        return;
    }
    if (bid < NEB3 + H1B) {
        // ---- layer-1 H from vertices; folds Wc = Win@W1, bc = bin@W1 ----
        __shared__ float Wc[3 * HD];
        __shared__ float bc[HD];
        if (t < HD) {
            float w0 = 0.f, w1 = 0.f, w2 = 0.f, bv = 0.f;
            for (int k = 0; k < HD; ++k) {
                float w = W1[k * HD + t];
                w0 = fmaf(Win[k], w, w0);
                w1 = fmaf(Win[128 + k], w, w1);
                w2 = fmaf(Win[256 + k], w, w2);
                bv = fmaf(bin[k], w, bv);
            }
            Wc[t] = w0; Wc[128 + t] = w1; Wc[256 + t] = w2; bc[t] = bv;
        }
        __syncthreads();
        for (int idx = (bid - NEB3) * 256 + t; idx < NV * HD; idx += H1B * 256) {
            int v = idx >> 7, c = idx & 127;
            float a = verts[v * 3 + 0], b = verts[v * 3 + 1], d = verts[v * 3 + 2];
            Hb[idx] = f2b(bc[c] + a * Wc[c] + b * Wc[128 + c] + d * Wc[256 + c]);
        }
        return;
    }
    if (bid < NEB3 + H1B + WTB) {
        // ---- W2,W3 [k][n] f32 -> Wt [l][n][k] bf16 ----
        int idx = (bid - NEB3 - H1B) * 256 + t;   // 0..32767
        if (idx < 2 * HD * HD) {
            int l = idx >> 14, r = idx & 16383;
            const float* W = (l == 0) ? W2 : W3;
            int n = r >> 7, k = r & 127;
            Wt[(l << 14) + n * HD + k] = f2b(W[k * HD + n]);
        }
        return;
    }
    // ---- batch boundary detection + pool zeroing ----
    int i = (bid - NEB3 - H1B - WTB) * 256 + t;
    if (i < NB * HD) pool[i] = 0.f;
    if (i < NV) {
        int b = batch[i];
        if (i == 0 || batch[i - 1] != b) gstart[b] = i;
        int bn = (i + 1 < NV) ? batch[i + 1] : -1;
        if (bn != b) gend[b] = i + 1;
    }
}

// ---------- per-bucket CSR: LDS-staged edges, hist -> scan -> fill ----------
__global__ __launch_bounds__(256) void k_bcsr(const int* __restrict__ ebuf,
                                              const int* __restrict__ bcursor,
                                              int* __restrict__ degi,
                                              float* __restrict__ dinv,
                                              int* __restrict__ rowstart,
                                              int* __restrict__ csr) {
    __shared__ int els[BCAP];
    __shared__ int h[DPB];
    __shared__ int sdata[DPB];
    int b = blockIdx.x, t = threadIdx.x, d0 = b * DPB;
    h[t] = 0;
    __syncthreads();
    int e0 = b << BSH;
    int n = bcursor[b];
    for (int i = t; i < n; i += 256) {
        int p = ebuf[e0 + i];
        if (i < BCAP) els[i] = p;
        atomicAdd(&h[p & 255], 1);
    }
    __syncthreads();
    int a = h[t];
    sdata[t] = a;
    __syncthreads();
    for (int off = 1; off < 256; off <<= 1) {
        int v = sdata[t];
        int add = (t >= off) ? sdata[t - off] : 0;
        __syncthreads();
        sdata[t] = v + add;
        __syncthreads();
    }
    int excl = (t == 0) ? 0 : sdata[t - 1];
    int v0 = d0 + t;
    if (v0 < NV) {
        rowstart[v0] = e0 + excl;
        degi[v0] = a;
        dinv[v0] = rsqrtf((float)a + 1.0f);
    }
    h[t] = e0 + excl;
    __syncthreads();
    for (int i = t; i < n; i += 256) {
        int p = (i < BCAP) ? els[i] : ebuf[e0 + i];
        int slot = atomicAdd(&h[p & 255], 1);
        csr[slot] = p >> 8;
    }
}

// ---------- H = X @ W via MFMA; 8 waves/block, 128 rows; Ws staged once, reused ----------
__global__ __launch_bounds__(512) void k_gemm_mfma(const unsigned short* __restrict__ Xb,
                                                   const unsigned short* __restrict__ Wt,
                                                   unsigned short* __restrict__ Hb) {
    __shared__ __align__(16) unsigned short Ws[128 * 136];   // 34.8 KB; reused for repack
    int t = threadIdx.x;
    {   // stage Wt -> LDS: thread loads 32 shorts (row t>>2, quarter (t&3)*32)
        int row = t >> 2;
        int qtr = (t & 3) << 5;
        const unsigned short* src = Wt + row * HD + qtr;
        unsigned short* dst = &Ws[row * 136 + qtr];
        #pragma unroll
        for (int i = 0; i < 4; ++i)
            *(bf16x8*)(dst + i * 8) = *(const bf16x8*)(src + i * 8);
    }
    int wave = t >> 6;                     // 0..7
    int lane = t & 63;
    int r = lane & 15;
    int g = lane >> 4;                     // 0..3
    int row0 = blockIdx.x * 128 + wave * 16;
    int arow = row0 + r;
    bool valid = arow < NV;

    bf16x8 afrag[4];
    const unsigned short* xp = Xb + (size_t)arow * HD + g * 8;
    #pragma unroll
    for (int ks = 0; ks < 4; ++ks) {
        if (valid) afrag[ks] = *(const bf16x8*)(xp + ks * 32);
        else       afrag[ks] = bf16x8{0, 0, 0, 0, 0, 0, 0, 0};
    }
    __syncthreads();

    f32x4 acc[8];
    #pragma unroll
    for (int nt = 0; nt < 8; ++nt) {
        acc[nt] = f32x4{0.f, 0.f, 0.f, 0.f};
        #pragma unroll
        for (int ks = 0; ks < 4; ++ks) {
            bf16x8 bfrag = *(const bf16x8*)&Ws[(nt * 16 + r) * 136 + g * 8 + ks * 32];
            acc[nt] = __builtin_amdgcn_mfma_f32_16x16x32_bf16(afrag[ks], bfrag, acc[nt], 0, 0, 0);
        }
    }
    __syncthreads();   // all waves done reading Ws; reuse as repack buffer
    // C/D: col = lane&15 (=r), row = g*4 + j -> per-wave region of Ws, then 16B stores
    unsigned short* hsw = Ws + wave * 16 * 136;   // 8 waves x 2176 = 17408 = 128*136, exact fit
    #pragma unroll
    for (int nt = 0; nt < 8; ++nt)
        #pragma unroll
        for (int j = 0; j < 4; ++j)
            hsw[(g * 4 + j) * 136 + nt * 16 + r] = f2b(acc[nt][j]);
    int row = lane >> 2;
    int grow = row0 + row;
    #pragma unroll
    for (int k = 0; k < 4; ++k) {
        int c = (lane & 3) + k * 4;      // chunk 0..15 (8 shorts each)
        bf16x8 val = *(const bf16x8*)&hsw[row * 136 + c * 8];
        if (grow < NV)
            *(bf16x8*)(Hb + (size_t)grow * HD + c * 8) = val;
    }
}

// ---------- aggregate: one wave per dst, quarter-waves over edges, bf16x8 rows ----------
__global__ __launch_bounds__(256) void k_agg(const unsigned short* __restrict__ H,
                                             const float* __restrict__ dinv,
                                             const int* __restrict__ rowstart,
                                             const int* __restrict__ degi,
                                             const int* __restrict__ csr_src,
                                             const float* __restrict__ bias,
                                             unsigned short* __restrict__ Xo) {
    int gtid = blockIdx.x * 256 + threadIdx.x;
    int v = gtid >> 6;
    if (v >= NV) return;
    int lane = threadIdx.x & 63;
    int q = lane >> 4;        // quarter 0..3: edges q, q+4, ...
    int l4 = lane & 15;       // col group: cols l4*8 .. l4*8+7
    float di = dinv[v];
    int rs = rowstart[v], len = degi[v];
    float a[8];
    if (q == 0) {
        float sc = di * di;
        bf16x8 hv = *(const bf16x8*)(H + (size_t)v * HD + l4 * 8);
        #pragma unroll
        for (int jj = 0; jj < 8; ++jj) a[jj] = b2f((unsigned short)hv[jj]) * sc;
    } else {
        #pragma unroll
        for (int jj = 0; jj < 8; ++jj) a[jj] = 0.f;
    }
    int cnt = (len - q + 3) >> 2;   // edges this quarter handles
    int idx = rs + q;
    int j = 0;
    for (; j + 1 < cnt; j += 2) {
        int s0 = csr_src[idx], s1 = csr_src[idx + 4];
        idx += 8;
        float w0 = dinv[s0] * di, w1 = dinv[s1] * di;
        bf16x8 h0 = *(const bf16x8*)(H + (size_t)s0 * HD + l4 * 8);
        bf16x8 h1 = *(const bf16x8*)(H + (size_t)s1 * HD + l4 * 8);
        #pragma unroll
        for (int jj = 0; jj < 8; ++jj) {
            a[jj] = fmaf(b2f((unsigned short)h0[jj]), w0, a[jj]);
            a[jj] = fmaf(b2f((unsigned short)h1[jj]), w1, a[jj]);
        }
    }
    if (j < cnt) {
        int s0 = csr_src[idx];
        float w0 = dinv[s0] * di;
        bf16x8 h0 = *(const bf16x8*)(H + (size_t)s0 * HD + l4 * 8);
        #pragma unroll
        for (int jj = 0; jj < 8; ++jj)
            a[jj] = fmaf(b2f((unsigned short)h0[jj]), w0, a[jj]);
    }
    // reduce across quarters (lanes l4, l4+16, l4+32, l4+48)
    #pragma unroll
    for (int jj = 0; jj < 8; ++jj) {
        a[jj] += __shfl_xor(a[jj], 16);
        a[jj] += __shfl_xor(a[jj], 32);
    }
    if (q == 0) {
        bf16x8 ov;
        #pragma unroll
        for (int jj = 0; jj < 8; ++jj)
            ov[jj] = (short)f2b(fmaxf(a[jj] + bias[l4 * 8 + jj], 0.f));
        *(bf16x8*)(Xo + (size_t)v * HD + l4 * 8) = ov;
    }
}

// ---------- mean pool: vectorized bf16x8 loads; LDS accumulate; few global atomics ----------
__global__ __launch_bounds__(256) void k_pool(const unsigned short* __restrict__ X,
                                              const int* __restrict__ batch,
                                              float* __restrict__ pool) {
    constexpr int CHUNK = (NV + 2047) / 2048;  // 49
    __shared__ float lp[2][HD];
    __shared__ int binfo[2];
    int t = threadIdx.x;
    int v0 = blockIdx.x * CHUNK;
    if (v0 >= NV) return;
    int vend = min(v0 + CHUNK, NV);
    if (t < 2 * HD) ((float*)lp)[t] = 0.f;
    if (t == 0) { binfo[0] = batch[v0]; binfo[1] = batch[vend - 1]; }
    __syncthreads();
    int b0 = binfo[0], b1 = binfo[1];
    int cg = t & 15;      // col group (8 cols)
    int ro = t >> 4;      // 0..15 row offset
    if (b1 - b0 <= 1) {
        float a0[8] = {}, a1[8] = {};
        for (int v = v0 + ro; v < vend; v += 16) {
            bf16x8 x = *(const bf16x8*)(X + (size_t)v * HD + cg * 8);
            if (batch[v] == b0) {
                #pragma unroll
                for (int jj = 0; jj < 8; ++jj) a0[jj] += b2f((unsigned short)x[jj]);
            } else {
                #pragma unroll
                for (int jj = 0; jj < 8; ++jj) a1[jj] += b2f((unsigned short)x[jj]);
            }
        }
        #pragma unroll
        for (int jj = 0; jj < 8; ++jj) {
            atomicAdd(&lp[0][cg * 8 + jj], a0[jj]);
            if (b1 != b0) atomicAdd(&lp[1][cg * 8 + jj], a1[jj]);
        }
        __syncthreads();
        int slot = t >> 7, col = t & 127;
        if (slot == 0 || b1 != b0)
            atomicAdd(&pool[(slot ? b1 : b0) * HD + col], lp[slot][col]);
    } else {
        float a[8] = {};
        int cur = -1;
        for (int v = v0 + ro; v < vend; v += 16) {
            int bb = batch[v];
            if (bb != cur) {
                if (cur >= 0) {
                    #pragma unroll
                    for (int jj = 0; jj < 8; ++jj) {
                        atomicAdd(&pool[cur * HD + cg * 8 + jj], a[jj]);
                        a[jj] = 0.f;
                    }
                }
                cur = bb;
            }
            bf16x8 x = *(const bf16x8*)(X + (size_t)v * HD + cg * 8);
            #pragma unroll
            for (int jj = 0; jj < 8; ++jj) a[jj] += b2f((unsigned short)x[jj]);
        }
        if (cur >= 0) {
            #pragma unroll
            for (int jj = 0; jj < 8; ++jj)
                atomicAdd(&pool[cur * HD + cg * 8 + jj], a[jj]);
        }
    }
}

// ---------- final: mean, linear, layernorm; one block per graph ----------
__global__ __launch_bounds__(256) void k_out(const float* __restrict__ pool,
                                             const int* __restrict__ gstart,
                                             const int* __restrict__ gend,
                                             const float* __restrict__ Wout,
                                             const float* __restrict__ bout,
                                             const float* __restrict__ gamma,
                                             const float* __restrict__ beta,
                                             float* __restrict__ out) {
    __shared__ float ps[HD];
    __shared__ float red[DM];
    int g = blockIdx.x, t = threadIdx.x;
    if (t < HD) {
        float cn = fmaxf((float)(gend[g] - gstart[g]), 1.0f);
        ps[t] = pool[g * HD + t] / cn;
    }
    __syncthreads();
    float acc = bout[t];
    #pragma unroll 8
    for (int k = 0; k < HD; ++k) acc = fmaf(ps[k], Wout[k * DM + t], acc);
    red[t] = acc; __syncthreads();
    for (int s2 = 128; s2 > 0; s2 >>= 1) {
        if (t < s2) red[t] += red[t + s2];
        __syncthreads();
    }
    float mu = red[0] * (1.0f / DM);
    __syncthreads();
    float d = acc - mu;
    red[t] = d * d; __syncthreads();
    for (int s2 = 128; s2 > 0; s2 >>= 1) {
        if (t < s2) red[t] += red[t + s2];
        __syncthreads();
    }
    float var = red[0] * (1.0f / DM);
    out[g * DM + t] = d * rsqrtf(var + EPSLN) * gamma[t] + beta[t];
}

extern "C" void kernel_launch(void* const* d_in, const int* in_sizes, int n_in,
                              void* d_out, int out_size, void* d_ws, size_t ws_size,
                              hipStream_t stream) {
    const float* verts = (const float*)d_in[0];
    const int*   ei    = (const int*)d_in[1];
    const int*   batch = (const int*)d_in[2];
    const float* Win   = (const float*)d_in[3];
    const float* bin   = (const float*)d_in[4];
    const float* W1    = (const float*)d_in[5];
    const float* b1    = (const float*)d_in[6];
    const float* W2    = (const float*)d_in[7];
    const float* b2    = (const float*)d_in[8];
    const float* W3    = (const float*)d_in[9];
    const float* b3    = (const float*)d_in[10];
    const float* Wout  = (const float*)d_in[11];
    const float* bout  = (const float*)d_in[12];
    const float* gamma = (const float*)d_in[13];
    const float* beta  = (const float*)d_in[14];
    float* out = (float*)d_out;

    char* wp = (char*)d_ws;
    auto alloc = [&](size_t bytes) -> char* {
        char* p = wp;
        wp += (bytes + 255) & ~(size_t)255;
        return p;
    };
    unsigned short* bufA = (unsigned short*)alloc((size_t)NV * HD * 2);
    unsigned short* bufB = (unsigned short*)alloc((size_t)NV * HD * 2);
    unsigned short* Wt   = (unsigned short*)alloc((size_t)2 * HD * HD * 2);
    int*   degi     = (int*)alloc((size_t)NV * 4);
    float* dinv     = (float*)alloc((size_t)NV * 4);
    int*   rowstart = (int*)alloc((size_t)NV * 4);
    int*   csr      = (int*)alloc((size_t)NBUCK * BCAP * 4);
    int*   ebuf     = (int*)alloc((size_t)NBUCK * BCAP * 4);
    float* pool     = (float*)alloc((size_t)NB * HD * 4);
    // small zero region: bcursor | gstart | gend
    size_t zb_cursor = ((size_t)NBUCK * 4 + 255) & ~(size_t)255;
    size_t zb_tot    = zb_cursor + 1024;
    char*  zblock   = alloc(zb_tot);
    int*   bcursor  = (int*)zblock;
    int*   gstart   = (int*)(zblock + zb_cursor);
    int*   gend     = (int*)(zblock + zb_cursor + 512);

    hipMemsetAsync(zblock, 0, zb_tot, stream);

    // fused init: edge scatter + layer-1 H + W transpose + boundaries/pool-zero
    k_init<<<NEB3 + H1B + WTB + BDB, 256, 0, stream>>>(verts, Win, bin, W1, W2, W3,
                                                       ei, batch, bcursor, ebuf,
                                                       bufA, Wt, gstart, gend, pool);
    // per-bucket CSR build (LDS-staged)
    k_bcsr<<<NBUCK, 256, 0, stream>>>(ebuf, bcursor, degi, dinv, rowstart, csr);

    int aggrid = (int)(((size_t)NV * 64 + 255) / 256);
    // layer 1
    k_agg<<<aggrid, 256, 0, stream>>>(bufA, dinv, rowstart, degi, csr, b1, bufB);
    k_gemm_mfma<<<(NV + 127) / 128, 512, 0, stream>>>(bufB, Wt, bufA);
    // layer 2
    k_agg<<<aggrid, 256, 0, stream>>>(bufA, dinv, rowstart, degi, csr, b2, bufB);
    k_gemm_mfma<<<(NV + 127) / 128, 512, 0, stream>>>(bufB, Wt + (size_t)HD * HD, bufA);
    // layer 3
    k_agg<<<aggrid, 256, 0, stream>>>(bufA, dinv, rowstart, degi, csr, b3, bufB);

    k_pool<<<2048, 256, 0, stream>>>(bufB, batch, pool);
    k_out<<<NB, 256, 0, stream>>>(pool, gstart, gend, Wout, bout, gamma, beta, out);
}